// Round 3
// baseline (6995.160 us; speedup 1.0000x reference)
//
#include <hip/hip_runtime.h>
#include <math.h>

#define N_NODES 100000
#define N_EDGES 1600000
#define F_IN    92
#define H_DIM   128
#define STEPS   6
#define G_GRAPHS 256
#define TH3     384   // 3*H

// ---------------- precompute: M2[i][j][k] = sum_c Wm[i][k][c] * w_ih[j][c] ----------------
// column-major fused weight: gi[j] = sum_k s[k] * M2[i][j][k]
__global__ void fuse_w_kernel(const float* __restrict__ Wm, const float* __restrict__ w_ih,
                              float* __restrict__ M2) {
    int ij = blockIdx.x;            // STEPS*384 = 2304 blocks
    int i  = ij / TH3;
    int j  = ij - i * TH3;
    int k  = threadIdx.x;           // 128 threads
    __shared__ float wj[H_DIM];
    wj[k] = w_ih[j * H_DIM + k];
    __syncthreads();
    const float* wr = Wm + ((size_t)i * H_DIM + k) * H_DIM;
    float acc = 0.f;
    #pragma unroll 4
    for (int c = 0; c < H_DIM; ++c) acc = fmaf(wj[c], wr[c], acc);
    M2[((size_t)i * TH3 + j) * H_DIM + k] = acc;
}

// ---------------- embed: h = tanh(x @ W_embed) ----------------
#define ET 16
__global__ void embed_kernel(const float* __restrict__ x, const float* __restrict__ We,
                             float* __restrict__ h) {
    int n0 = blockIdx.x * ET;       // 6250 blocks, exact
    int j  = threadIdx.x;           // 128 threads
    __shared__ float xs[ET * F_IN];
    for (int i = j; i < ET * F_IN; i += H_DIM) xs[i] = x[n0 * F_IN + i];
    __syncthreads();
    float acc[ET];
    #pragma unroll
    for (int n = 0; n < ET; ++n) acc[n] = 0.f;
    const float4* xs4 = (const float4*)xs;   // row = 92 floats = 23 float4
    for (int k4 = 0; k4 < F_IN / 4; ++k4) {
        int k = k4 * 4;
        float w0 = We[(k + 0) * H_DIM + j];
        float w1 = We[(k + 1) * H_DIM + j];
        float w2 = We[(k + 2) * H_DIM + j];
        float w3 = We[(k + 3) * H_DIM + j];
        #pragma unroll
        for (int n = 0; n < ET; ++n) {
            float4 a = xs4[n * (F_IN / 4) + k4];
            acc[n] = fmaf(a.x, w0, acc[n]);
            acc[n] = fmaf(a.y, w1, acc[n]);
            acc[n] = fmaf(a.z, w2, acc[n]);
            acc[n] = fmaf(a.w, w3, acc[n]);
        }
    }
    #pragma unroll
    for (int n = 0; n < ET; ++n) {
        float e2 = __expf(2.f * acc[n]);
        h[(n0 + n) * H_DIM + j] = 1.f - 2.f / (e2 + 1.f);
    }
}

// ---------------- CSR build: histogram -> scan -> bucket fill ----------------
__global__ void hist_kernel(const int* __restrict__ dst, int* __restrict__ count) {
    int e = blockIdx.x * 256 + threadIdx.x;
    if (e < N_EDGES) atomicAdd(&count[dst[e]], 1);
}

__global__ void scan_block_kernel(const int* __restrict__ count, int* __restrict__ offs,
                                  int* __restrict__ blockSums) {
    __shared__ int tmp[256];
    int i = blockIdx.x * 256 + threadIdx.x;
    int t = threadIdx.x;
    int v = (i < N_NODES) ? count[i] : 0;
    tmp[t] = v;
    __syncthreads();
    for (int d = 1; d < 256; d <<= 1) {
        int add = (t >= d) ? tmp[t - d] : 0;
        __syncthreads();
        tmp[t] += add;
        __syncthreads();
    }
    if (i < N_NODES) offs[i] = tmp[t] - v;
    if (t == 255) blockSums[blockIdx.x] = tmp[255];
}

__global__ void scan_sums_kernel(int* __restrict__ blockSums, int nb) {  // 1 block, 512 thr
    __shared__ int tmp[512];
    int t = threadIdx.x;
    int v = (t < nb) ? blockSums[t] : 0;
    tmp[t] = v;
    __syncthreads();
    for (int d = 1; d < 512; d <<= 1) {
        int add = (t >= d) ? tmp[t - d] : 0;
        __syncthreads();
        tmp[t] += add;
        __syncthreads();
    }
    if (t < nb) blockSums[t] = tmp[t] - v;
}

__global__ void scan_add_kernel(int* __restrict__ offs, const int* __restrict__ blockSums) {
    int i = blockIdx.x * 256 + threadIdx.x;
    if (i < N_NODES) offs[i] += blockSums[blockIdx.x];
    if (i == 0) offs[N_NODES] = N_EDGES;
}

__global__ void fill_kernel(const int* __restrict__ src, const int* __restrict__ dst,
                            const int* __restrict__ offs, int* __restrict__ cursor,
                            int* __restrict__ srcSorted) {
    int e = blockIdx.x * 256 + threadIdx.x;
    if (e < N_EDGES) {
        int d = dst[e];
        int pos = atomicAdd(&cursor[d], 1);
        srcSorted[offs[d] + pos] = src[e];
    }
}

// ---------------- gather: s[n] = sum over incoming edges of h[src] ----------------
__global__ void gather_kernel(const float4* __restrict__ h4, const int* __restrict__ offs,
                              const int* __restrict__ srcSorted, float4* __restrict__ s4) {
    int tid  = blockIdx.x * 256 + threadIdx.x;   // 12500 blocks, exact
    int node = tid >> 5;
    int c    = tid & 31;
    int beg = offs[node], end = offs[node + 1];
    float4 acc = make_float4(0.f, 0.f, 0.f, 0.f);
    int i = beg;
    for (; i + 4 <= end; i += 4) {
        int s0 = srcSorted[i], s1 = srcSorted[i + 1];
        int s2 = srcSorted[i + 2], s3 = srcSorted[i + 3];
        float4 v0 = h4[(size_t)s0 * 32 + c];
        float4 v1 = h4[(size_t)s1 * 32 + c];
        float4 v2 = h4[(size_t)s2 * 32 + c];
        float4 v3 = h4[(size_t)s3 * 32 + c];
        acc.x += v0.x + v1.x + v2.x + v3.x;
        acc.y += v0.y + v1.y + v2.y + v3.y;
        acc.z += v0.z + v1.z + v2.z + v3.z;
        acc.w += v0.w + v1.w + v2.w + v3.w;
    }
    for (; i < end; ++i) {
        int sn = srcSorted[i];
        float4 v = h4[(size_t)sn * 32 + c];
        acc.x += v.x; acc.y += v.y; acc.z += v.z; acc.w += v.w;
    }
    s4[(size_t)node * 32 + c] = acc;
}

// ---------------- fused GRU step ----------------
// 256 threads: tt = t&127 owns gate cols (tt, tt+128, tt+256); half = t>>7 owns nodes
// [half*8, half*8+8). Weights column-major: M2i[j][k], w_hh[j][k] (native layout!).
#define GT 16
__global__ __launch_bounds__(256, 4) void gru_kernel(const float* __restrict__ s,
                                                     float* __restrict__ h,
                                                     const float* __restrict__ M2i,
                                                     const float* __restrict__ w_hh,
                                                     const float* __restrict__ b_ih,
                                                     const float* __restrict__ b_hh) {
    int n0 = blockIdx.x * GT;       // 6250 blocks, exact
    int t  = threadIdx.x;           // 256
    int tt   = t & 127;
    int half = t >> 7;
    __shared__ float As[GT * H_DIM];   // 8KB
    __shared__ float Ah[GT * H_DIM];   // 8KB

    {   // vectorized stage: 512 float4 per array, 2 per thread
        float4* Asw = (float4*)As;
        float4* Ahw = (float4*)Ah;
        const float4* sg = (const float4*)(s + (size_t)n0 * H_DIM);
        const float4* hg = (const float4*)(h + (size_t)n0 * H_DIM);
        #pragma unroll
        for (int i = 0; i < 2; ++i) {
            Asw[t + i * 256] = sg[t + i * 256];
            Ahw[t + i * 256] = hg[t + i * 256];
        }
    }
    __syncthreads();

    float aIr[8], aIz[8], aIn[8], aHr[8], aHz[8], aHn[8];
    #pragma unroll
    for (int n = 0; n < 8; ++n) {
        aIr[n] = 0.f; aIz[n] = 0.f; aIn[n] = 0.f;
        aHr[n] = 0.f; aHz[n] = 0.f; aHn[n] = 0.f;
    }

    const float4* Wi0 = (const float4*)(M2i  + (size_t)(tt      ) * H_DIM);
    const float4* Wi1 = (const float4*)(M2i  + (size_t)(tt + 128) * H_DIM);
    const float4* Wi2 = (const float4*)(M2i  + (size_t)(tt + 256) * H_DIM);
    const float4* Wh0 = (const float4*)(w_hh + (size_t)(tt      ) * H_DIM);
    const float4* Wh1 = (const float4*)(w_hh + (size_t)(tt + 128) * H_DIM);
    const float4* Wh2 = (const float4*)(w_hh + (size_t)(tt + 256) * H_DIM);
    const float4* As4 = (const float4*)As;
    const float4* Ah4 = (const float4*)Ah;

    for (int k4 = 0; k4 < H_DIM / 4; ++k4) {
        float4 mi0 = Wi0[k4], mi1 = Wi1[k4], mi2 = Wi2[k4];
        float4 mh0 = Wh0[k4], mh1 = Wh1[k4], mh2 = Wh2[k4];
        #pragma unroll
        for (int n = 0; n < 8; ++n) {
            float4 a = As4[(half * 8 + n) * 32 + k4];
            float4 b = Ah4[(half * 8 + n) * 32 + k4];
            aIr[n] = fmaf(a.x, mi0.x, aIr[n]); aIr[n] = fmaf(a.y, mi0.y, aIr[n]);
            aIr[n] = fmaf(a.z, mi0.z, aIr[n]); aIr[n] = fmaf(a.w, mi0.w, aIr[n]);
            aIz[n] = fmaf(a.x, mi1.x, aIz[n]); aIz[n] = fmaf(a.y, mi1.y, aIz[n]);
            aIz[n] = fmaf(a.z, mi1.z, aIz[n]); aIz[n] = fmaf(a.w, mi1.w, aIz[n]);
            aIn[n] = fmaf(a.x, mi2.x, aIn[n]); aIn[n] = fmaf(a.y, mi2.y, aIn[n]);
            aIn[n] = fmaf(a.z, mi2.z, aIn[n]); aIn[n] = fmaf(a.w, mi2.w, aIn[n]);
            aHr[n] = fmaf(b.x, mh0.x, aHr[n]); aHr[n] = fmaf(b.y, mh0.y, aHr[n]);
            aHr[n] = fmaf(b.z, mh0.z, aHr[n]); aHr[n] = fmaf(b.w, mh0.w, aHr[n]);
            aHz[n] = fmaf(b.x, mh1.x, aHz[n]); aHz[n] = fmaf(b.y, mh1.y, aHz[n]);
            aHz[n] = fmaf(b.z, mh1.z, aHz[n]); aHz[n] = fmaf(b.w, mh1.w, aHz[n]);
            aHn[n] = fmaf(b.x, mh2.x, aHn[n]); aHn[n] = fmaf(b.y, mh2.y, aHn[n]);
            aHn[n] = fmaf(b.z, mh2.z, aHn[n]); aHn[n] = fmaf(b.w, mh2.w, aHn[n]);
        }
    }

    float bir = b_ih[tt], biz = b_ih[tt + 128], bin = b_ih[tt + 256];
    float bhr = b_hh[tt], bhz = b_hh[tt + 128], bhn = b_hh[tt + 256];
    #pragma unroll
    for (int n = 0; n < 8; ++n) {
        int node = half * 8 + n;
        float r = 1.f / (1.f + __expf(-((aIr[n] + bir) + (aHr[n] + bhr))));
        float z = 1.f / (1.f + __expf(-((aIz[n] + biz) + (aHz[n] + bhz))));
        float pre = (aIn[n] + bin) + r * (aHn[n] + bhn);
        float e2 = __expf(2.f * pre);
        float cand = 1.f - 2.f / (e2 + 1.f);        // tanh, overflow-safe
        float hold = Ah[node * H_DIM + tt];
        h[(size_t)(n0 + node) * H_DIM + tt] = (1.f - z) * cand + z * hold;
    }
}

// ---------------- pool + relu + prediction head ----------------
__global__ void pool_kernel(const float* __restrict__ h, const int* __restrict__ batch,
                            const float* __restrict__ w_pred, const float* __restrict__ b_pred,
                            float* __restrict__ out) {
    int g = blockIdx.x;             // 256 blocks
    int t = threadIdx.x;            // 128 threads
    __shared__ int bounds[2];
    __shared__ float red[2];
    if (t < 2) {
        int target = g + t;
        int lo = 0, hi = N_NODES;
        while (lo < hi) {
            int mid = (lo + hi) >> 1;
            if (batch[mid] < target) lo = mid + 1; else hi = mid;
        }
        bounds[t] = lo;
    }
    __syncthreads();
    int lo = bounds[0], hi = bounds[1];
    float sum = 0.f;
    for (int n = lo; n < hi; ++n) sum += h[n * H_DIM + t];
    int cnt = hi - lo;
    float pooled = sum / fmaxf((float)cnt, 1.f);
    pooled = fmaxf(pooled, 0.f);
    float v = pooled * w_pred[t];
    #pragma unroll
    for (int off = 32; off > 0; off >>= 1) v += __shfl_down(v, off);
    if ((t & 63) == 0) red[t >> 6] = v;
    __syncthreads();
    if (t == 0) out[g] = red[0] + red[1] + b_pred[0];
}

extern "C" void kernel_launch(void* const* d_in, const int* in_sizes, int n_in,
                              void* d_out, int out_size, void* d_ws, size_t ws_size,
                              hipStream_t stream) {
    const float* x      = (const float*)d_in[0];
    const int*   ei     = (const int*)d_in[1];    // [2,E]: src = ei, dst = ei+E
    const int*   batch  = (const int*)d_in[2];
    const float* We     = (const float*)d_in[3];
    const float* Wm     = (const float*)d_in[4];
    const float* w_ih   = (const float*)d_in[5];
    const float* w_hh   = (const float*)d_in[6];  // [384][128] — used directly (col-major)
    const float* b_ih   = (const float*)d_in[7];
    const float* b_hh   = (const float*)d_in[8];
    const float* w_pred = (const float*)d_in[9];
    const float* b_pred = (const float*)d_in[10];
    float* out = (float*)d_out;

    float* h    = (float*)d_ws;                        // N*H
    float* s    = h + (size_t)N_NODES * H_DIM;         // N*H
    float* M6   = s + (size_t)N_NODES * H_DIM;         // 6*384*128 (col-major per step)
    int* offs      = (int*)(M6 + (size_t)STEPS * TH3 * H_DIM); // N+1 ints
    int* srcSorted = offs + (N_NODES + 1);               // E ints
    // CSR-build temporaries overlaid on s (s only used inside the step loop)
    int* count     = (int*)s;
    int* cursor    = count + N_NODES;
    int* blockSums = cursor + N_NODES;                   // 391 ints

    const int* esrc = ei;
    const int* edst = ei + N_EDGES;
    const int EB = (N_EDGES + 255) / 256;                // 6250
    const int NB = (N_NODES + 255) / 256;                // 391

    // --- build CSR (once per launch) ---
    hipMemsetAsync(count, 0, 2 * (size_t)N_NODES * sizeof(int), stream);  // count + cursor
    hist_kernel<<<EB, 256, 0, stream>>>(edst, count);
    scan_block_kernel<<<NB, 256, 0, stream>>>(count, offs, blockSums);
    scan_sums_kernel<<<1, 512, 0, stream>>>(blockSums, NB);
    scan_add_kernel<<<NB, 256, 0, stream>>>(offs, blockSums);
    fill_kernel<<<EB, 256, 0, stream>>>(esrc, edst, offs, cursor, srcSorted);

    fuse_w_kernel<<<STEPS * TH3, H_DIM, 0, stream>>>(Wm, w_ih, M6);
    embed_kernel<<<N_NODES / ET, H_DIM, 0, stream>>>(x, We, h);

    for (int i = 0; i < STEPS; ++i) {
        gather_kernel<<<N_NODES / 8, 256, 0, stream>>>((const float4*)h, offs, srcSorted,
                                                       (float4*)s);
        gru_kernel<<<N_NODES / GT, 256, 0, stream>>>(s, h, M6 + (size_t)i * TH3 * H_DIM,
                                                     w_hh, b_ih, b_hh);
    }

    pool_kernel<<<G_GRAPHS, H_DIM, 0, stream>>>(h, batch, w_pred, b_pred, out);
}

// Round 4
// 2734.951 us; speedup vs baseline: 2.5577x; 2.5577x over previous
//
#include <hip/hip_runtime.h>
#include <math.h>

#define N_NODES 100000
#define N_PAD   100032          // 1563 * 64
#define N_EDGES 1600000
#define F_IN    92
#define H_DIM   128
#define STEPS   6
#define G_GRAPHS 256
#define TH3     384

typedef __attribute__((ext_vector_type(8))) short bf16x8;
typedef __attribute__((ext_vector_type(4))) float f32x4;

__device__ __forceinline__ unsigned short f2bf(float x) {   // fp32 -> bf16 RNE
    unsigned u = __float_as_uint(x);
    return (unsigned short)((u + 0x7fffu + ((u >> 16) & 1u)) >> 16);
}
__device__ __forceinline__ float bf2f(unsigned short h) {
    return __uint_as_float(((unsigned)h) << 16);
}

// ---------------- precompute: M2[i][j][k] = sum_c Wm[i][k][c] * w_ih[j][c] (col-major) ----
__global__ void fuse_w_kernel(const float* __restrict__ Wm, const float* __restrict__ w_ih,
                              float* __restrict__ M2) {
    int ij = blockIdx.x;            // STEPS*384 = 2304 blocks
    int i  = ij / TH3;
    int j  = ij - i * TH3;
    int k  = threadIdx.x;           // 128 threads
    __shared__ float wj[H_DIM];
    wj[k] = w_ih[j * H_DIM + k];
    __syncthreads();
    const float* wr = Wm + ((size_t)i * H_DIM + k) * H_DIM;
    float acc = 0.f;
    #pragma unroll 4
    for (int c = 0; c < H_DIM; ++c) acc = fmaf(wj[c], wr[c], acc);
    M2[((size_t)i * TH3 + j) * H_DIM + k] = acc;
}

// ---------------- pack weights into MFMA B-fragment order, split hi/lo bf16 ----------------
// fragIdx = (mat*3+g)*32 + ct*4 + kc ; element: B[k = kc*32+(lane>>4)*8+jj][col j = g*128+ct*16+(lane&15)]
// mat 0..5 -> M2 step mat ; mat 6 -> w_hh (native [384][128] col-major)
__global__ void pack_kernel(const float* __restrict__ M6, const float* __restrict__ w_hh,
                            unsigned short* __restrict__ PBhi, unsigned short* __restrict__ PBlo) {
    int b    = blockIdx.x;          // 672 = 21*32
    int lane = threadIdx.x;         // 64
    int kc   = b & 3;
    int ct   = (b >> 2) & 7;
    int mg   = b >> 5;              // mat*3+g, 0..20
    int g    = mg % 3;
    int mat  = mg / 3;
    int j    = g * 128 + ct * 16 + (lane & 15);
    int k0   = kc * 32 + (lane >> 4) * 8;
    size_t outBase = ((size_t)b * 64 + lane) * 8;
    #pragma unroll
    for (int jj = 0; jj < 8; ++jj) {
        int k = k0 + jj;
        float v = (mat < 6) ? M6[((size_t)mat * TH3 + j) * H_DIM + k]
                            : w_hh[(size_t)j * H_DIM + k];
        unsigned short hv = f2bf(v);
        PBhi[outBase + jj] = hv;
        PBlo[outBase + jj] = f2bf(v - bf2f(hv));
    }
}

// ---------------- embed: h = tanh(x @ W_embed), output split bf16 hi/lo ----------------
#define ET 16
__global__ void embed_kernel(const float* __restrict__ x, const float* __restrict__ We,
                             unsigned short* __restrict__ h_hi, unsigned short* __restrict__ h_lo) {
    int n0 = blockIdx.x * ET;       // 6250 blocks, exact
    int j  = threadIdx.x;           // 128 threads
    __shared__ float xs[ET * F_IN];
    for (int i = j; i < ET * F_IN; i += H_DIM) xs[i] = x[n0 * F_IN + i];
    __syncthreads();
    float acc[ET];
    #pragma unroll
    for (int n = 0; n < ET; ++n) acc[n] = 0.f;
    const float4* xs4 = (const float4*)xs;
    for (int k4 = 0; k4 < F_IN / 4; ++k4) {
        int k = k4 * 4;
        float w0 = We[(k + 0) * H_DIM + j];
        float w1 = We[(k + 1) * H_DIM + j];
        float w2 = We[(k + 2) * H_DIM + j];
        float w3 = We[(k + 3) * H_DIM + j];
        #pragma unroll
        for (int n = 0; n < ET; ++n) {
            float4 a = xs4[n * (F_IN / 4) + k4];
            acc[n] = fmaf(a.x, w0, acc[n]);
            acc[n] = fmaf(a.y, w1, acc[n]);
            acc[n] = fmaf(a.z, w2, acc[n]);
            acc[n] = fmaf(a.w, w3, acc[n]);
        }
    }
    #pragma unroll
    for (int n = 0; n < ET; ++n) {
        float e2 = __expf(2.f * acc[n]);
        float v  = 1.f - 2.f / (e2 + 1.f);
        size_t o = (size_t)(n0 + n) * H_DIM + j;
        unsigned short hv = f2bf(v);
        h_hi[o] = hv;
        h_lo[o] = f2bf(v - bf2f(hv));
    }
}

// ---------------- CSR build: histogram -> scan -> bucket fill ----------------
__global__ void hist_kernel(const int* __restrict__ dst, int* __restrict__ count) {
    int e = blockIdx.x * 256 + threadIdx.x;
    if (e < N_EDGES) atomicAdd(&count[dst[e]], 1);
}

__global__ void scan_block_kernel(const int* __restrict__ count, int* __restrict__ offs,
                                  int* __restrict__ blockSums) {
    __shared__ int tmp[256];
    int i = blockIdx.x * 256 + threadIdx.x;
    int t = threadIdx.x;
    int v = (i < N_NODES) ? count[i] : 0;
    tmp[t] = v;
    __syncthreads();
    for (int d = 1; d < 256; d <<= 1) {
        int add = (t >= d) ? tmp[t - d] : 0;
        __syncthreads();
        tmp[t] += add;
        __syncthreads();
    }
    if (i < N_NODES) offs[i] = tmp[t] - v;
    if (t == 255) blockSums[blockIdx.x] = tmp[255];
}

__global__ void scan_sums_kernel(int* __restrict__ blockSums, int nb) {  // 1 block, 512 thr
    __shared__ int tmp[512];
    int t = threadIdx.x;
    int v = (t < nb) ? blockSums[t] : 0;
    tmp[t] = v;
    __syncthreads();
    for (int d = 1; d < 512; d <<= 1) {
        int add = (t >= d) ? tmp[t - d] : 0;
        __syncthreads();
        tmp[t] += add;
        __syncthreads();
    }
    if (t < nb) blockSums[t] = tmp[t] - v;
}

__global__ void scan_add_kernel(int* __restrict__ offs, const int* __restrict__ blockSums) {
    int i = blockIdx.x * 256 + threadIdx.x;
    if (i < N_NODES) offs[i] += blockSums[blockIdx.x];
    if (i == 0) offs[N_NODES] = N_EDGES;
}

__global__ void fill_kernel(const int* __restrict__ src, const int* __restrict__ dst,
                            const int* __restrict__ offs, int* __restrict__ cursor,
                            int* __restrict__ srcSorted) {
    int e = blockIdx.x * 256 + threadIdx.x;
    if (e < N_EDGES) {
        int d = dst[e];
        int pos = atomicAdd(&cursor[d], 1);
        srcSorted[offs[d] + pos] = src[e];
    }
}

// ---------------- gather: s[n] = sum over incoming edges of h[src] (bf16 hi/lo IO) --------
__global__ void gather_kernel(const unsigned short* __restrict__ h_hi,
                              const unsigned short* __restrict__ h_lo,
                              const int* __restrict__ offs, const int* __restrict__ srcS,
                              unsigned short* __restrict__ s_hi, unsigned short* __restrict__ s_lo) {
    int tid  = blockIdx.x * 256 + threadIdx.x;   // 12500 blocks, exact
    int node = tid >> 5;
    int c4   = (tid & 31) * 4;
    int beg = offs[node], end = offs[node + 1];
    float a0 = 0.f, a1 = 0.f, a2 = 0.f, a3 = 0.f;
    int i = beg;
    for (; i + 2 <= end; i += 2) {
        int n0 = srcS[i], n1 = srcS[i + 1];
        ushort4 h0 = *(const ushort4*)(h_hi + (size_t)n0 * H_DIM + c4);
        ushort4 l0 = *(const ushort4*)(h_lo + (size_t)n0 * H_DIM + c4);
        ushort4 h1 = *(const ushort4*)(h_hi + (size_t)n1 * H_DIM + c4);
        ushort4 l1 = *(const ushort4*)(h_lo + (size_t)n1 * H_DIM + c4);
        a0 += (bf2f(h0.x) + bf2f(l0.x)) + (bf2f(h1.x) + bf2f(l1.x));
        a1 += (bf2f(h0.y) + bf2f(l0.y)) + (bf2f(h1.y) + bf2f(l1.y));
        a2 += (bf2f(h0.z) + bf2f(l0.z)) + (bf2f(h1.z) + bf2f(l1.z));
        a3 += (bf2f(h0.w) + bf2f(l0.w)) + (bf2f(h1.w) + bf2f(l1.w));
    }
    if (i < end) {
        int n0 = srcS[i];
        ushort4 h0 = *(const ushort4*)(h_hi + (size_t)n0 * H_DIM + c4);
        ushort4 l0 = *(const ushort4*)(h_lo + (size_t)n0 * H_DIM + c4);
        a0 += bf2f(h0.x) + bf2f(l0.x);
        a1 += bf2f(h0.y) + bf2f(l0.y);
        a2 += bf2f(h0.z) + bf2f(l0.z);
        a3 += bf2f(h0.w) + bf2f(l0.w);
    }
    size_t o = (size_t)node * H_DIM + c4;
    ushort4 sh, sl;
    sh.x = f2bf(a0); sl.x = f2bf(a0 - bf2f(sh.x));
    sh.y = f2bf(a1); sl.y = f2bf(a1 - bf2f(sh.y));
    sh.z = f2bf(a2); sl.z = f2bf(a2 - bf2f(sh.z));
    sh.w = f2bf(a3); sl.w = f2bf(a3 - bf2f(sh.w));
    *(ushort4*)(s_hi + o) = sh;
    *(ushort4*)(s_lo + o) = sl;
}

// ---------------- fused GRU step via MFMA (split-bf16, 3 products per GEMM) ----------------
// Block = 4 waves; wave w owns nodes [nt*64+w*16, +16) x all 128 gate-channels.
// In-place h update is race-free: each wave reads/writes only its own 16 rows.
__global__ __launch_bounds__(256, 2) void gru_mfma_kernel(
    const unsigned short* __restrict__ s_hi, const unsigned short* __restrict__ s_lo,
    unsigned short* __restrict__ h_hi, unsigned short* __restrict__ h_lo,
    const unsigned short* __restrict__ PBhi, const unsigned short* __restrict__ PBlo,
    int matI,
    const float* __restrict__ b_ih, const float* __restrict__ b_hh)
{
    int nt   = blockIdx.x;          // 1563 blocks (last has 32 pad rows)
    int lane = threadIdx.x & 63;
    int w    = threadIdx.x >> 6;
    int rowA = nt * 64 + w * 16 + (lane & 15);       // A-fragment row for this lane
    int kOff = (lane >> 4) * 8;                      // A-fragment k offset

    f32x4 accI[3][8], accH[3][8];
    #pragma unroll
    for (int g = 0; g < 3; ++g)
        #pragma unroll
        for (int ct = 0; ct < 8; ++ct) {
            accI[g][ct] = (f32x4){0.f, 0.f, 0.f, 0.f};
            accH[g][ct] = (f32x4){0.f, 0.f, 0.f, 0.f};
        }

    const size_t aBase = (size_t)rowA * H_DIM + kOff;
    const int fI0 = matI * 3;
    for (int kc = 0; kc < 4; ++kc) {
        bf16x8 aSh = *(const bf16x8*)(s_hi + aBase + kc * 32);
        bf16x8 aSl = *(const bf16x8*)(s_lo + aBase + kc * 32);
        bf16x8 aHh = *(const bf16x8*)(h_hi + aBase + kc * 32);
        bf16x8 aHl = *(const bf16x8*)(h_lo + aBase + kc * 32);
        #pragma unroll
        for (int g = 0; g < 3; ++g) {
            #pragma unroll
            for (int ct = 0; ct < 8; ++ct) {
                size_t oI = ((size_t)((fI0 + g) * 32 + ct * 4 + kc) * 64 + lane) * 8;
                size_t oH = ((size_t)((18  + g) * 32 + ct * 4 + kc) * 64 + lane) * 8;
                bf16x8 bIh = *(const bf16x8*)(PBhi + oI);
                bf16x8 bIl = *(const bf16x8*)(PBlo + oI);
                bf16x8 bHh = *(const bf16x8*)(PBhi + oH);
                bf16x8 bHl = *(const bf16x8*)(PBlo + oH);
                accI[g][ct] = __builtin_amdgcn_mfma_f32_16x16x32_bf16(aSh, bIh, accI[g][ct], 0, 0, 0);
                accI[g][ct] = __builtin_amdgcn_mfma_f32_16x16x32_bf16(aSl, bIh, accI[g][ct], 0, 0, 0);
                accI[g][ct] = __builtin_amdgcn_mfma_f32_16x16x32_bf16(aSh, bIl, accI[g][ct], 0, 0, 0);
                accH[g][ct] = __builtin_amdgcn_mfma_f32_16x16x32_bf16(aHh, bHh, accH[g][ct], 0, 0, 0);
                accH[g][ct] = __builtin_amdgcn_mfma_f32_16x16x32_bf16(aHl, bHh, accH[g][ct], 0, 0, 0);
                accH[g][ct] = __builtin_amdgcn_mfma_f32_16x16x32_bf16(aHh, bHl, accH[g][ct], 0, 0, 0);
            }
        }
    }

    // epilogue: C layout col=lane&15, row=(lane>>4)*4+reg — all 6 gate values per (node,c)
    // land in the SAME lane, so GRU math is fully thread-local.
    int rowC = nt * 64 + w * 16 + (lane >> 4) * 4;
    int cLoc = lane & 15;
    #pragma unroll
    for (int ct = 0; ct < 8; ++ct) {
        int c = ct * 16 + cLoc;
        float bir = b_ih[c], biz = b_ih[128 + c], bin = b_ih[256 + c];
        float bhr = b_hh[c], bhz = b_hh[128 + c], bhn = b_hh[256 + c];
        #pragma unroll
        for (int r = 0; r < 4; ++r) {
            int node = rowC + r;
            if (node < N_NODES) {
                size_t off = (size_t)node * H_DIM + c;
                float gr = (accI[0][ct][r] + bir) + (accH[0][ct][r] + bhr);
                float gz = (accI[1][ct][r] + biz) + (accH[1][ct][r] + bhz);
                float rr = 1.f / (1.f + __expf(-gr));
                float zz = 1.f / (1.f + __expf(-gz));
                float pre = (accI[2][ct][r] + bin) + rr * (accH[2][ct][r] + bhn);
                float e2 = __expf(2.f * pre);
                float cand = 1.f - 2.f / (e2 + 1.f);      // tanh, overflow-safe
                float hold = bf2f(h_hi[off]) + bf2f(h_lo[off]);
                float hn = (1.f - zz) * cand + zz * hold;
                unsigned short hv = f2bf(hn);
                h_hi[off] = hv;
                h_lo[off] = f2bf(hn - bf2f(hv));
            }
        }
    }
}

// ---------------- pool + relu + prediction head ----------------
__global__ void pool_kernel(const unsigned short* __restrict__ h_hi,
                            const unsigned short* __restrict__ h_lo,
                            const int* __restrict__ batch,
                            const float* __restrict__ w_pred, const float* __restrict__ b_pred,
                            float* __restrict__ out) {
    int g = blockIdx.x;             // 256 blocks
    int t = threadIdx.x;            // 128 threads
    __shared__ int bounds[2];
    __shared__ float red[2];
    if (t < 2) {
        int target = g + t;
        int lo = 0, hi = N_NODES;
        while (lo < hi) {
            int mid = (lo + hi) >> 1;
            if (batch[mid] < target) lo = mid + 1; else hi = mid;
        }
        bounds[t] = lo;
    }
    __syncthreads();
    int lo = bounds[0], hi = bounds[1];
    float sum = 0.f;
    for (int n = lo; n < hi; ++n) {
        size_t o = (size_t)n * H_DIM + t;
        sum += bf2f(h_hi[o]) + bf2f(h_lo[o]);
    }
    int cnt = hi - lo;
    float pooled = sum / fmaxf((float)cnt, 1.f);
    pooled = fmaxf(pooled, 0.f);
    float v = pooled * w_pred[t];
    #pragma unroll
    for (int off = 32; off > 0; off >>= 1) v += __shfl_down(v, off);
    if ((t & 63) == 0) red[t >> 6] = v;
    __syncthreads();
    if (t == 0) out[g] = red[0] + red[1] + b_pred[0];
}

extern "C" void kernel_launch(void* const* d_in, const int* in_sizes, int n_in,
                              void* d_out, int out_size, void* d_ws, size_t ws_size,
                              hipStream_t stream) {
    const float* x      = (const float*)d_in[0];
    const int*   ei     = (const int*)d_in[1];    // [2,E]: src = ei, dst = ei+E
    const int*   batch  = (const int*)d_in[2];
    const float* We     = (const float*)d_in[3];
    const float* Wm     = (const float*)d_in[4];
    const float* w_ih   = (const float*)d_in[5];
    const float* w_hh   = (const float*)d_in[6];  // [384][128] native col-major
    const float* b_ih   = (const float*)d_in[7];
    const float* b_hh   = (const float*)d_in[8];
    const float* w_pred = (const float*)d_in[9];
    const float* b_pred = (const float*)d_in[10];
    float* out = (float*)d_out;

    const size_t HN = (size_t)N_PAD * H_DIM;      // padded rows for MFMA tiles
    unsigned short* h_hi = (unsigned short*)d_ws;
    unsigned short* h_lo = h_hi + HN;
    unsigned short* s_hi = h_lo + HN;
    unsigned short* s_lo = s_hi + HN;
    float* M6 = (float*)(s_lo + HN);                               // 6*384*128 fp32
    unsigned short* PBhi = (unsigned short*)(M6 + (size_t)STEPS * TH3 * H_DIM);
    unsigned short* PBlo = PBhi + 21 * 32 * 64 * 8;                // 344064 each
    int* offs      = (int*)(PBlo + 21 * 32 * 64 * 8);              // N+1
    int* srcSorted = offs + (N_NODES + 1);                         // E
    // CSR temporaries overlaid on s_hi (s written only later by gather)
    int* count     = (int*)s_hi;
    int* cursor    = count + N_NODES;
    int* blockSums = cursor + N_NODES;

    const int* esrc = ei;
    const int* edst = ei + N_EDGES;
    const int EB = (N_EDGES + 255) / 256;                // 6250
    const int NB = (N_NODES + 255) / 256;                // 391

    hipMemsetAsync(count, 0, 2 * (size_t)N_NODES * sizeof(int), stream);
    hist_kernel<<<EB, 256, 0, stream>>>(edst, count);
    scan_block_kernel<<<NB, 256, 0, stream>>>(count, offs, blockSums);
    scan_sums_kernel<<<1, 512, 0, stream>>>(blockSums, NB);
    scan_add_kernel<<<NB, 256, 0, stream>>>(offs, blockSums);
    fill_kernel<<<EB, 256, 0, stream>>>(esrc, edst, offs, cursor, srcSorted);

    fuse_w_kernel<<<STEPS * TH3, H_DIM, 0, stream>>>(Wm, w_ih, M6);
    pack_kernel<<<21 * 32, 64, 0, stream>>>(M6, w_hh, PBhi, PBlo);
    embed_kernel<<<N_NODES / ET, H_DIM, 0, stream>>>(x, We, h_hi, h_lo);

    for (int i = 0; i < STEPS; ++i) {
        gather_kernel<<<(N_NODES * 32) / 256, 256, 0, stream>>>(h_hi, h_lo, offs, srcSorted,
                                                                s_hi, s_lo);
        gru_mfma_kernel<<<N_PAD / 64, 256, 0, stream>>>(s_hi, s_lo, h_hi, h_lo,
                                                        PBhi, PBlo, i, b_ih, b_hh);
    }

    pool_kernel<<<G_GRAPHS, H_DIM, 0, stream>>>(h_hi, h_lo, batch, w_pred, b_pred, out);
}

// Round 5
// 2238.377 us; speedup vs baseline: 3.1251x; 1.2218x over previous
//
#include <hip/hip_runtime.h>
#include <math.h>

#define N_NODES 100000
#define N_PAD   100032          // 1563 * 64
#define N_EDGES 1600000
#define F_IN    92
#define H_DIM   128
#define STEPS   6
#define G_GRAPHS 256
#define TH3     384

typedef __attribute__((ext_vector_type(8))) short bf16x8;
typedef __attribute__((ext_vector_type(4))) float f32x4;

__device__ __forceinline__ unsigned short f2bf(float x) {   // fp32 -> bf16 RNE
    unsigned u = __float_as_uint(x);
    return (unsigned short)((u + 0x7fffu + ((u >> 16) & 1u)) >> 16);
}
__device__ __forceinline__ float bf2f(unsigned short h) {
    return __uint_as_float(((unsigned)h) << 16);
}

// ---------------- precompute: M2[i][j][k] = sum_c Wm[i][k][c] * w_ih[j][c] (col-major) ----
__global__ void fuse_w_kernel(const float* __restrict__ Wm, const float* __restrict__ w_ih,
                              float* __restrict__ M2) {
    int ij = blockIdx.x;            // STEPS*384 = 2304 blocks
    int i  = ij / TH3;
    int j  = ij - i * TH3;
    int k  = threadIdx.x;           // 128 threads
    __shared__ float wj[H_DIM];
    wj[k] = w_ih[j * H_DIM + k];
    __syncthreads();
    const float* wr = Wm + ((size_t)i * H_DIM + k) * H_DIM;
    float acc = 0.f;
    #pragma unroll 4
    for (int c = 0; c < H_DIM; ++c) acc = fmaf(wj[c], wr[c], acc);
    M2[((size_t)i * TH3 + j) * H_DIM + k] = acc;
}

// ---------------- pack weights into MFMA B-fragment order, split hi/lo bf16 ----------------
// fragIdx = (mat*3+g)*32 + ct*4 + kc ; element: B[k = kc*32+(lane>>4)*8+jj][col j = g*128+ct*16+(lane&15)]
// mat 0..5 -> M2 step mat ; mat 6 -> w_hh (native [384][128] col-major)
__global__ void pack_kernel(const float* __restrict__ M6, const float* __restrict__ w_hh,
                            unsigned short* __restrict__ PBhi, unsigned short* __restrict__ PBlo) {
    int b    = blockIdx.x;          // 672 = 21*32
    int lane = threadIdx.x;         // 64
    int kc   = b & 3;
    int ct   = (b >> 2) & 7;
    int mg   = b >> 5;              // mat*3+g, 0..20
    int g    = mg % 3;
    int mat  = mg / 3;
    int j    = g * 128 + ct * 16 + (lane & 15);
    int k0   = kc * 32 + (lane >> 4) * 8;
    size_t outBase = ((size_t)b * 64 + lane) * 8;
    #pragma unroll
    for (int jj = 0; jj < 8; ++jj) {
        int k = k0 + jj;
        float v = (mat < 6) ? M6[((size_t)mat * TH3 + j) * H_DIM + k]
                            : w_hh[(size_t)j * H_DIM + k];
        unsigned short hv = f2bf(v);
        PBhi[outBase + jj] = hv;
        PBlo[outBase + jj] = f2bf(v - bf2f(hv));
    }
}

// ---------------- embed: h = tanh(x @ W_embed), output split bf16 hi/lo ----------------
#define ET 16
__global__ void embed_kernel(const float* __restrict__ x, const float* __restrict__ We,
                             unsigned short* __restrict__ h_hi, unsigned short* __restrict__ h_lo) {
    int n0 = blockIdx.x * ET;       // 6250 blocks, exact
    int j  = threadIdx.x;           // 128 threads
    __shared__ float xs[ET * F_IN];
    for (int i = j; i < ET * F_IN; i += H_DIM) xs[i] = x[n0 * F_IN + i];
    __syncthreads();
    float acc[ET];
    #pragma unroll
    for (int n = 0; n < ET; ++n) acc[n] = 0.f;
    const float4* xs4 = (const float4*)xs;
    for (int k4 = 0; k4 < F_IN / 4; ++k4) {
        int k = k4 * 4;
        float w0 = We[(k + 0) * H_DIM + j];
        float w1 = We[(k + 1) * H_DIM + j];
        float w2 = We[(k + 2) * H_DIM + j];
        float w3 = We[(k + 3) * H_DIM + j];
        #pragma unroll
        for (int n = 0; n < ET; ++n) {
            float4 a = xs4[n * (F_IN / 4) + k4];
            acc[n] = fmaf(a.x, w0, acc[n]);
            acc[n] = fmaf(a.y, w1, acc[n]);
            acc[n] = fmaf(a.z, w2, acc[n]);
            acc[n] = fmaf(a.w, w3, acc[n]);
        }
    }
    #pragma unroll
    for (int n = 0; n < ET; ++n) {
        float e2 = __expf(2.f * acc[n]);
        float v  = 1.f - 2.f / (e2 + 1.f);
        size_t o = (size_t)(n0 + n) * H_DIM + j;
        unsigned short hv = f2bf(v);
        h_hi[o] = hv;
        h_lo[o] = f2bf(v - bf2f(hv));
    }
}

// ---------------- CSR build: histogram -> scan -> bucket fill ----------------
__global__ void hist_kernel(const int* __restrict__ dst, int* __restrict__ count) {
    int e = blockIdx.x * 256 + threadIdx.x;
    if (e < N_EDGES) atomicAdd(&count[dst[e]], 1);
}

__global__ void scan_block_kernel(const int* __restrict__ count, int* __restrict__ offs,
                                  int* __restrict__ blockSums) {
    __shared__ int tmp[256];
    int i = blockIdx.x * 256 + threadIdx.x;
    int t = threadIdx.x;
    int v = (i < N_NODES) ? count[i] : 0;
    tmp[t] = v;
    __syncthreads();
    for (int d = 1; d < 256; d <<= 1) {
        int add = (t >= d) ? tmp[t - d] : 0;
        __syncthreads();
        tmp[t] += add;
        __syncthreads();
    }
    if (i < N_NODES) offs[i] = tmp[t] - v;
    if (t == 255) blockSums[blockIdx.x] = tmp[255];
}

__global__ void scan_sums_kernel(int* __restrict__ blockSums, int nb) {  // 1 block, 512 thr
    __shared__ int tmp[512];
    int t = threadIdx.x;
    int v = (t < nb) ? blockSums[t] : 0;
    tmp[t] = v;
    __syncthreads();
    for (int d = 1; d < 512; d <<= 1) {
        int add = (t >= d) ? tmp[t - d] : 0;
        __syncthreads();
        tmp[t] += add;
        __syncthreads();
    }
    if (t < nb) blockSums[t] = tmp[t] - v;
}

__global__ void scan_add_kernel(int* __restrict__ offs, const int* __restrict__ blockSums) {
    int i = blockIdx.x * 256 + threadIdx.x;
    if (i < N_NODES) offs[i] += blockSums[blockIdx.x];
    if (i == 0) offs[N_NODES] = N_EDGES;
}

__global__ void fill_kernel(const int* __restrict__ src, const int* __restrict__ dst,
                            const int* __restrict__ offs, int* __restrict__ cursor,
                            int* __restrict__ srcSorted) {
    int e = blockIdx.x * 256 + threadIdx.x;
    if (e < N_EDGES) {
        int d = dst[e];
        int pos = atomicAdd(&cursor[d], 1);
        srcSorted[offs[d] + pos] = src[e];
    }
}

// ---------------- gather: s[n] = sum over incoming edges of h[src] (bf16 hi/lo IO) --------
__global__ void gather_kernel(const unsigned short* __restrict__ h_hi,
                              const unsigned short* __restrict__ h_lo,
                              const int* __restrict__ offs, const int* __restrict__ srcS,
                              unsigned short* __restrict__ s_hi, unsigned short* __restrict__ s_lo) {
    int tid  = blockIdx.x * 256 + threadIdx.x;   // 12500 blocks, exact
    int node = tid >> 5;
    int c4   = (tid & 31) * 4;
    int beg = offs[node], end = offs[node + 1];
    float a0 = 0.f, a1 = 0.f, a2 = 0.f, a3 = 0.f;
    int i = beg;
    for (; i + 2 <= end; i += 2) {
        int n0 = srcS[i], n1 = srcS[i + 1];
        ushort4 h0 = *(const ushort4*)(h_hi + (size_t)n0 * H_DIM + c4);
        ushort4 l0 = *(const ushort4*)(h_lo + (size_t)n0 * H_DIM + c4);
        ushort4 h1 = *(const ushort4*)(h_hi + (size_t)n1 * H_DIM + c4);
        ushort4 l1 = *(const ushort4*)(h_lo + (size_t)n1 * H_DIM + c4);
        a0 += (bf2f(h0.x) + bf2f(l0.x)) + (bf2f(h1.x) + bf2f(l1.x));
        a1 += (bf2f(h0.y) + bf2f(l0.y)) + (bf2f(h1.y) + bf2f(l1.y));
        a2 += (bf2f(h0.z) + bf2f(l0.z)) + (bf2f(h1.z) + bf2f(l1.z));
        a3 += (bf2f(h0.w) + bf2f(l0.w)) + (bf2f(h1.w) + bf2f(l1.w));
    }
    if (i < end) {
        int n0 = srcS[i];
        ushort4 h0 = *(const ushort4*)(h_hi + (size_t)n0 * H_DIM + c4);
        ushort4 l0 = *(const ushort4*)(h_lo + (size_t)n0 * H_DIM + c4);
        a0 += bf2f(h0.x) + bf2f(l0.x);
        a1 += bf2f(h0.y) + bf2f(l0.y);
        a2 += bf2f(h0.z) + bf2f(l0.z);
        a3 += bf2f(h0.w) + bf2f(l0.w);
    }
    size_t o = (size_t)node * H_DIM + c4;
    ushort4 sh, sl;
    sh.x = f2bf(a0); sl.x = f2bf(a0 - bf2f(sh.x));
    sh.y = f2bf(a1); sl.y = f2bf(a1 - bf2f(sh.y));
    sh.z = f2bf(a2); sl.z = f2bf(a2 - bf2f(sh.z));
    sh.w = f2bf(a3); sl.w = f2bf(a3 - bf2f(sh.w));
    *(ushort4*)(s_hi + o) = sh;
    *(ushort4*)(s_lo + o) = sl;
}

// ---------------- fused GRU step via MFMA (split-bf16, 3 products per GEMM) ----------------
// Block = 8 waves = 64 rows x 128 channels. Wave w owns 64 rows x 16 channels (ct = w):
// 24 C-tiles (4 row-subtiles x 3 gates x 2 sides) = 96 acc VGPRs. Epilogue thread-local
// (all 6 gate values for a (node,c) in the same lane). Blocks own disjoint row-tiles;
// intra-block (epilogue write vs other waves' A reads) closed by one __syncthreads.
__global__ __launch_bounds__(512, 2) void gru_mfma_kernel(
    const unsigned short* __restrict__ s_hi, const unsigned short* __restrict__ s_lo,
    unsigned short* __restrict__ h_hi, unsigned short* __restrict__ h_lo,
    const unsigned short* __restrict__ PBhi, const unsigned short* __restrict__ PBlo,
    int matI,
    const float* __restrict__ b_ih, const float* __restrict__ b_hh)
{
    int nt   = blockIdx.x;          // 1563 blocks (last has 32 pad rows)
    int lane = threadIdx.x & 63;
    int ct   = threadIdx.x >> 6;    // wave id = channel tile, 0..7
    int rowBase = nt * 64;
    int rowA = rowBase + (lane & 15);                // +rs*16 for A-fragment row
    int kOff = (lane >> 4) * 8;                      // A-fragment k offset

    f32x4 accI[3][4], accH[3][4];   // [gate][row-subtile]
    #pragma unroll
    for (int g = 0; g < 3; ++g)
        #pragma unroll
        for (int rs = 0; rs < 4; ++rs) {
            accI[g][rs] = (f32x4){0.f, 0.f, 0.f, 0.f};
            accH[g][rs] = (f32x4){0.f, 0.f, 0.f, 0.f};
        }

    const int fI0 = matI * 3;
    for (int kc = 0; kc < 4; ++kc) {
        const size_t aOff = (size_t)kc * 32 + kOff;
        // ---- I side: A = s (hi/lo), B = fused M (hi/lo) ----
        bf16x8 aSh[4], aSl[4];
        #pragma unroll
        for (int rs = 0; rs < 4; ++rs) {
            size_t ab = (size_t)(rowA + rs * 16) * H_DIM + aOff;
            aSh[rs] = *(const bf16x8*)(s_hi + ab);
            aSl[rs] = *(const bf16x8*)(s_lo + ab);
        }
        #pragma unroll
        for (int g = 0; g < 3; ++g) {
            size_t oI = ((size_t)((fI0 + g) * 32 + ct * 4 + kc) * 64 + lane) * 8;
            bf16x8 bh = *(const bf16x8*)(PBhi + oI);
            bf16x8 bl = *(const bf16x8*)(PBlo + oI);
            #pragma unroll
            for (int rs = 0; rs < 4; ++rs) {
                accI[g][rs] = __builtin_amdgcn_mfma_f32_16x16x32_bf16(aSh[rs], bh, accI[g][rs], 0, 0, 0);
                accI[g][rs] = __builtin_amdgcn_mfma_f32_16x16x32_bf16(aSl[rs], bh, accI[g][rs], 0, 0, 0);
                accI[g][rs] = __builtin_amdgcn_mfma_f32_16x16x32_bf16(aSh[rs], bl, accI[g][rs], 0, 0, 0);
            }
        }
        // ---- H side: A = h (hi/lo), B = w_hh (hi/lo, mat 6) ----
        bf16x8 aHh[4], aHl[4];
        #pragma unroll
        for (int rs = 0; rs < 4; ++rs) {
            size_t ab = (size_t)(rowA + rs * 16) * H_DIM + aOff;
            aHh[rs] = *(const bf16x8*)(h_hi + ab);
            aHl[rs] = *(const bf16x8*)(h_lo + ab);
        }
        #pragma unroll
        for (int g = 0; g < 3; ++g) {
            size_t oH = ((size_t)((18 + g) * 32 + ct * 4 + kc) * 64 + lane) * 8;
            bf16x8 bh = *(const bf16x8*)(PBhi + oH);
            bf16x8 bl = *(const bf16x8*)(PBlo + oH);
            #pragma unroll
            for (int rs = 0; rs < 4; ++rs) {
                accH[g][rs] = __builtin_amdgcn_mfma_f32_16x16x32_bf16(aHh[rs], bh, accH[g][rs], 0, 0, 0);
                accH[g][rs] = __builtin_amdgcn_mfma_f32_16x16x32_bf16(aHl[rs], bh, accH[g][rs], 0, 0, 0);
                accH[g][rs] = __builtin_amdgcn_mfma_f32_16x16x32_bf16(aHh[rs], bl, accH[g][rs], 0, 0, 0);
            }
        }
    }

    __syncthreads();   // all waves done reading s/h rows before in-place h writes

    // epilogue: C layout col=lane&15, row=(lane>>4)*4+reg — thread-local GRU math
    int c   = ct * 16 + (lane & 15);                 // channel in [0,128)
    float bir = b_ih[c], biz = b_ih[128 + c], bin = b_ih[256 + c];
    float bhr = b_hh[c], bhz = b_hh[128 + c], bhn = b_hh[256 + c];
    int rowC = rowBase + (lane >> 4) * 4;
    #pragma unroll
    for (int rs = 0; rs < 4; ++rs) {
        #pragma unroll
        for (int r = 0; r < 4; ++r) {
            int node = rowC + rs * 16 + r;
            if (node < N_NODES) {
                size_t off = (size_t)node * H_DIM + c;
                float gr = (accI[0][rs][r] + bir) + (accH[0][rs][r] + bhr);
                float gz = (accI[1][rs][r] + biz) + (accH[1][rs][r] + bhz);
                float rr = 1.f / (1.f + __expf(-gr));
                float zz = 1.f / (1.f + __expf(-gz));
                float pre = (accI[2][rs][r] + bin) + rr * (accH[2][rs][r] + bhn);
                float e2 = __expf(2.f * pre);
                float cand = 1.f - 2.f / (e2 + 1.f);      // tanh, overflow-safe
                float hold = bf2f(h_hi[off]) + bf2f(h_lo[off]);
                float hn = (1.f - zz) * cand + zz * hold;
                unsigned short hv = f2bf(hn);
                h_hi[off] = hv;
                h_lo[off] = f2bf(hn - bf2f(hv));
            }
        }
    }
}

// ---------------- pool + relu + prediction head ----------------
__global__ void pool_kernel(const unsigned short* __restrict__ h_hi,
                            const unsigned short* __restrict__ h_lo,
                            const int* __restrict__ batch,
                            const float* __restrict__ w_pred, const float* __restrict__ b_pred,
                            float* __restrict__ out) {
    int g = blockIdx.x;             // 256 blocks
    int t = threadIdx.x;            // 128 threads
    __shared__ int bounds[2];
    __shared__ float red[2];
    if (t < 2) {
        int target = g + t;
        int lo = 0, hi = N_NODES;
        while (lo < hi) {
            int mid = (lo + hi) >> 1;
            if (batch[mid] < target) lo = mid + 1; else hi = mid;
        }
        bounds[t] = lo;
    }
    __syncthreads();
    int lo = bounds[0], hi = bounds[1];
    float sum = 0.f;
    for (int n = lo; n < hi; ++n) {
        size_t o = (size_t)n * H_DIM + t;
        sum += bf2f(h_hi[o]) + bf2f(h_lo[o]);
    }
    int cnt = hi - lo;
    float pooled = sum / fmaxf((float)cnt, 1.f);
    pooled = fmaxf(pooled, 0.f);
    float v = pooled * w_pred[t];
    #pragma unroll
    for (int off = 32; off > 0; off >>= 1) v += __shfl_down(v, off);
    if ((t & 63) == 0) red[t >> 6] = v;
    __syncthreads();
    if (t == 0) out[g] = red[0] + red[1] + b_pred[0];
}

extern "C" void kernel_launch(void* const* d_in, const int* in_sizes, int n_in,
                              void* d_out, int out_size, void* d_ws, size_t ws_size,
                              hipStream_t stream) {
    const float* x      = (const float*)d_in[0];
    const int*   ei     = (const int*)d_in[1];    // [2,E]: src = ei, dst = ei+E
    const int*   batch  = (const int*)d_in[2];
    const float* We     = (const float*)d_in[3];
    const float* Wm     = (const float*)d_in[4];
    const float* w_ih   = (const float*)d_in[5];
    const float* w_hh   = (const float*)d_in[6];  // [384][128] native col-major
    const float* b_ih   = (const float*)d_in[7];
    const float* b_hh   = (const float*)d_in[8];
    const float* w_pred = (const float*)d_in[9];
    const float* b_pred = (const float*)d_in[10];
    float* out = (float*)d_out;

    const size_t HN = (size_t)N_PAD * H_DIM;      // padded rows for MFMA tiles
    unsigned short* h_hi = (unsigned short*)d_ws;
    unsigned short* h_lo = h_hi + HN;
    unsigned short* s_hi = h_lo + HN;
    unsigned short* s_lo = s_hi + HN;
    float* M6 = (float*)(s_lo + HN);                               // 6*384*128 fp32
    unsigned short* PBhi = (unsigned short*)(M6 + (size_t)STEPS * TH3 * H_DIM);
    unsigned short* PBlo = PBhi + 21 * 32 * 64 * 8;                // 344064 each
    int* offs      = (int*)(PBlo + 21 * 32 * 64 * 8);              // N+1
    int* srcSorted = offs + (N_NODES + 1);                         // E
    // CSR temporaries overlaid on s_hi (s written only later by gather)
    int* count     = (int*)s_hi;
    int* cursor    = count + N_NODES;
    int* blockSums = cursor + N_NODES;

    const int* esrc = ei;
    const int* edst = ei + N_EDGES;
    const int EB = (N_EDGES + 255) / 256;                // 6250
    const int NB = (N_NODES + 255) / 256;                // 391

    hipMemsetAsync(count, 0, 2 * (size_t)N_NODES * sizeof(int), stream);
    hist_kernel<<<EB, 256, 0, stream>>>(edst, count);
    scan_block_kernel<<<NB, 256, 0, stream>>>(count, offs, blockSums);
    scan_sums_kernel<<<1, 512, 0, stream>>>(blockSums, NB);
    scan_add_kernel<<<NB, 256, 0, stream>>>(offs, blockSums);
    fill_kernel<<<EB, 256, 0, stream>>>(esrc, edst, offs, cursor, srcSorted);

    fuse_w_kernel<<<STEPS * TH3, H_DIM, 0, stream>>>(Wm, w_ih, M6);
    pack_kernel<<<21 * 32, 64, 0, stream>>>(M6, w_hh, PBhi, PBlo);
    embed_kernel<<<N_NODES / ET, H_DIM, 0, stream>>>(x, We, h_hi, h_lo);

    for (int i = 0; i < STEPS; ++i) {
        gather_kernel<<<(N_NODES * 32) / 256, 256, 0, stream>>>(h_hi, h_lo, offs, srcSorted,
                                                                s_hi, s_lo);
        gru_mfma_kernel<<<N_PAD / 64, 512, 0, stream>>>(s_hi, s_lo, h_hi, h_lo,
                                                        PBhi, PBlo, i, b_ih, b_hh);
    }

    pool_kernel<<<G_GRAPHS, H_DIM, 0, stream>>>(h_hi, h_lo, batch, w_pred, b_pred, out);
}